// Round 2
// baseline (2633.000 us; speedup 1.0000x reference)
//
#include <hip/hip_runtime.h>
#include <hip/hip_bf16.h>
#include <cstdint>
#include <cstddef>

#define B_   64
#define T_   196
#define D_   768
#define H_   12
#define HID_ 64
#define NT_  (B_ * T_)   // 12544

__device__ __forceinline__ float bf2f(uint16_t u) {
    uint32_t x = ((uint32_t)u) << 16;
    return __builtin_bit_cast(float, x);
}
__device__ __forceinline__ uint16_t f2bf(float f) {
    uint32_t x = __builtin_bit_cast(uint32_t, f);
    uint32_t r = (x + 0x7fffu + ((x >> 16) & 1u)) >> 16;
    return (uint16_t)r;
}

// ---------------------------------------------------------------------------
// K1: C_bf16[n][m] = sum_k A[n][k] * Bw[m][k] + bias[m]
//     A: [N][K] f32 row-major, Bw: [M][K] f32 row-major (NT gemm, K contiguous)
// grid: (N/64, M/64), block 256, 4x4 per thread
// ---------------------------------------------------------------------------
template<int KDIM>
__global__ __launch_bounds__(256)
void gemm_nt_bf16out(const float* __restrict__ A, const float* __restrict__ Bw,
                     const float* __restrict__ bias, uint16_t* __restrict__ C,
                     int Mtot)
{
    __shared__ float As[16][68];
    __shared__ float Bs[16][68];
    const int tid = threadIdx.x;
    const int n0 = blockIdx.x * 64, m0 = blockIdx.y * 64;
    const int lr = tid >> 2;          // 0..63
    const int lk = (tid & 3) << 2;    // 0,4,8,12
    const int tx = tid & 15, ty = tid >> 4;

    float acc[4][4];
#pragma unroll
    for (int i = 0; i < 4; i++)
#pragma unroll
        for (int jj = 0; jj < 4; jj++) acc[i][jj] = 0.f;

    const float* Ap = A + (size_t)(n0 + lr) * KDIM + lk;
    const float* Bp = Bw + (size_t)(m0 + lr) * KDIM + lk;

    for (int k0 = 0; k0 < KDIM; k0 += 16) {
        float4 av = *(const float4*)(Ap + k0);
        float4 bv = *(const float4*)(Bp + k0);
        As[lk + 0][lr] = av.x; As[lk + 1][lr] = av.y;
        As[lk + 2][lr] = av.z; As[lk + 3][lr] = av.w;
        Bs[lk + 0][lr] = bv.x; Bs[lk + 1][lr] = bv.y;
        Bs[lk + 2][lr] = bv.z; Bs[lk + 3][lr] = bv.w;
        __syncthreads();
#pragma unroll
        for (int k = 0; k < 16; k++) {
            float4 a = *(const float4*)&As[k][ty * 4];
            float4 b = *(const float4*)&Bs[k][tx * 4];
            float a4[4] = {a.x, a.y, a.z, a.w};
            float b4[4] = {b.x, b.y, b.z, b.w};
#pragma unroll
            for (int i = 0; i < 4; i++)
#pragma unroll
                for (int jj = 0; jj < 4; jj++) acc[i][jj] += a4[i] * b4[jj];
        }
        __syncthreads();
    }
#pragma unroll
    for (int i = 0; i < 4; i++) {
        const int n = n0 + ty * 4 + i;
#pragma unroll
        for (int jj = 0; jj < 4; jj++) {
            const int m = m0 + tx * 4 + jj;
            C[(size_t)n * Mtot + m] = f2bf(acc[i][jj] + bias[m]);
        }
    }
}

// ---------------------------------------------------------------------------
// K3: C_f32[n][m] = sum_k bf2f(A[n][k]) * Bw[m][k] + bias[m]
// ---------------------------------------------------------------------------
template<int KDIM>
__global__ __launch_bounds__(256)
void gemm_nt_bf16in_f32out(const uint16_t* __restrict__ A, const float* __restrict__ Bw,
                           const float* __restrict__ bias, float* __restrict__ C,
                           int Mtot)
{
    __shared__ float As[16][68];
    __shared__ float Bs[16][68];
    const int tid = threadIdx.x;
    const int n0 = blockIdx.x * 64, m0 = blockIdx.y * 64;
    const int lr = tid >> 2;
    const int lk = (tid & 3) << 2;
    const int tx = tid & 15, ty = tid >> 4;

    float acc[4][4];
#pragma unroll
    for (int i = 0; i < 4; i++)
#pragma unroll
        for (int jj = 0; jj < 4; jj++) acc[i][jj] = 0.f;

    const uint16_t* Ap = A + (size_t)(n0 + lr) * KDIM + lk;
    const float* Bp = Bw + (size_t)(m0 + lr) * KDIM + lk;

    for (int k0 = 0; k0 < KDIM; k0 += 16) {
        uint2 au = *(const uint2*)(Ap + k0);   // 4 bf16
        float4 bv = *(const float4*)(Bp + k0);
        As[lk + 0][lr] = bf2f((uint16_t)(au.x & 0xffffu));
        As[lk + 1][lr] = bf2f((uint16_t)(au.x >> 16));
        As[lk + 2][lr] = bf2f((uint16_t)(au.y & 0xffffu));
        As[lk + 3][lr] = bf2f((uint16_t)(au.y >> 16));
        Bs[lk + 0][lr] = bv.x; Bs[lk + 1][lr] = bv.y;
        Bs[lk + 2][lr] = bv.z; Bs[lk + 3][lr] = bv.w;
        __syncthreads();
#pragma unroll
        for (int k = 0; k < 16; k++) {
            float4 a = *(const float4*)&As[k][ty * 4];
            float4 b = *(const float4*)&Bs[k][tx * 4];
            float a4[4] = {a.x, a.y, a.z, a.w};
            float b4[4] = {b.x, b.y, b.z, b.w};
#pragma unroll
            for (int i = 0; i < 4; i++)
#pragma unroll
                for (int jj = 0; jj < 4; jj++) acc[i][jj] += a4[i] * b4[jj];
        }
        __syncthreads();
    }
#pragma unroll
    for (int i = 0; i < 4; i++) {
        const int n = n0 + ty * 4 + i;
#pragma unroll
        for (int jj = 0; jj < 4; jj++) {
            const int m = m0 + tx * 4 + jj;
            C[(size_t)n * Mtot + m] = acc[i][jj] + bias[m];
        }
    }
}

// ---------------------------------------------------------------------------
// K2: per-head bidirectional LSTM recurrence.
// grid = 24 chains (head,dir) x 8 batch-tiles of 8  = 192 blocks, 256 threads.
// Thread g owns gate row g (Wih/Whh rows in 128 VGPRs) for 8 batches.
// __launch_bounds__(256, 1): 1 wave/EU min -> full VGPR budget so wi[]/wh[]
// stay register-resident (R1 had VGPR_Count=84 -> weights in scratch, 11x
// over the VALU-issue floor).
// ---------------------------------------------------------------------------
__global__ __launch_bounds__(256, 1)
void lstm_rec(const uint16_t* __restrict__ xp,         // [NT][768] bf16
              const float* __restrict__ Wih_f, const float* __restrict__ Whh_f,
              const float* __restrict__ bih_f, const float* __restrict__ bhh_f,
              const float* __restrict__ Wih_r, const float* __restrict__ Whh_r,
              const float* __restrict__ bih_r, const float* __restrict__ bhh_r,
              uint16_t* __restrict__ y)                // [NT][1536] bf16
{
    const int blk   = blockIdx.x;
    const int btile = blk & 7;
    const int chain = blk >> 3;        // 0..23
    const int head  = chain % H_;
    const int dir   = chain / H_;
    const int b0    = btile * 8;
    const int g     = threadIdx.x;     // 0..255

    const float* Wih = dir ? Wih_r : Wih_f;
    const float* Whh = dir ? Whh_r : Whh_f;
    const float* bih = dir ? bih_r : bih_f;
    const float* bhh = dir ? bhh_r : bhh_f;

    __shared__ float xs[512];     // [8][64]
    __shared__ float hs[512];     // [8][64]
    __shared__ float Gs[2048];    // [8][256]

    float wi[64], wh[64];
    {
        const float* wip = Wih + ((size_t)head * 256 + g) * 64;
        const float* whp = Whh + ((size_t)head * 256 + g) * 64;
#pragma unroll
        for (int d = 0; d < 64; d += 4) {
            float4 a = *(const float4*)(wip + d);
            wi[d] = a.x; wi[d + 1] = a.y; wi[d + 2] = a.z; wi[d + 3] = a.w;
            float4 b = *(const float4*)(whp + d);
            wh[d] = b.x; wh[d + 1] = b.y; wh[d + 2] = b.z; wh[d + 3] = b.w;
        }
    }
    const float biasg = bih[head * 256 + g] + bhh[head * 256 + g];

    const int j  = g & 63;
    const int bq = g >> 6;
    float c0 = 0.f, c1 = 0.f;

    // init h = 0, prefetch x slice for t=0
    hs[g] = 0.f; hs[g + 256] = 0.f;
    {
        const int tt0 = dir ? (T_ - 1) : 0;
        const int idx = g * 2;
        const int bb = idx >> 6, dd = idx & 63;
        const uint16_t* xr = xp + ((size_t)(b0 + bb) * T_ + tt0) * D_ + head * 64 + dd;
        xs[idx] = bf2f(xr[0]); xs[idx + 1] = bf2f(xr[1]);
    }
    __syncthreads();

    for (int s = 0; s < T_; ++s) {
        const int tt = dir ? (T_ - 1 - s) : s;

        float acc[8];
#pragma unroll
        for (int b = 0; b < 8; b++) acc[b] = biasg;

#pragma unroll
        for (int d = 0; d < 64; d += 4) {
#pragma unroll
            for (int b = 0; b < 8; b++) {
                float4 xv = *(const float4*)&xs[b * 64 + d];
                acc[b] += xv.x * wi[d] + xv.y * wi[d + 1] + xv.z * wi[d + 2] + xv.w * wi[d + 3];
            }
        }
#pragma unroll
        for (int d = 0; d < 64; d += 4) {
#pragma unroll
            for (int b = 0; b < 8; b++) {
                float4 hv = *(const float4*)&hs[b * 64 + d];
                acc[b] += hv.x * wh[d] + hv.y * wh[d + 1] + hv.z * wh[d + 2] + hv.w * wh[d + 3];
            }
        }
#pragma unroll
        for (int b = 0; b < 8; b++) Gs[b * 256 + g] = acc[b];
        __syncthreads();   // G ready; everyone done reading xs/hs

#pragma unroll
        for (int half = 0; half < 2; ++half) {
            const int b = bq + half * 4;
            const float gi = Gs[b * 256 + j];
            const float gf = Gs[b * 256 + 64 + j];
            const float gg = Gs[b * 256 + 128 + j];
            const float go = Gs[b * 256 + 192 + j];
            const float i_ = 1.f / (1.f + __expf(-gi));
            const float f_ = 1.f / (1.f + __expf(-gf));
            const float g_ = 1.f - 2.f / (1.f + __expf(2.f * gg));
            const float o_ = 1.f / (1.f + __expf(-go));
            float& c = half ? c1 : c0;
            c = f_ * c + i_ * g_;
            const float h = o_ * (1.f - 2.f / (1.f + __expf(2.f * c)));
            hs[b * 64 + j] = h;
            y[((size_t)(b0 + b) * T_ + tt) * 1536 + dir * 768 + head * 64 + j] = f2bf(h);
        }
        if (s + 1 < T_) {
            const int tn = dir ? (T_ - 2 - s) : (s + 1);
            const int idx = g * 2;
            const int bb = idx >> 6, dd = idx & 63;
            const uint16_t* xr = xp + ((size_t)(b0 + bb) * T_ + tn) * D_ + head * 64 + dd;
            xs[idx] = bf2f(xr[0]); xs[idx + 1] = bf2f(xr[1]);
        }
        __syncthreads();   // hs / xs ready for next step
    }
}

// ---------------------------------------------------------------------------
extern "C" void kernel_launch(void* const* d_in, const int* in_sizes, int n_in,
                              void* d_out, int out_size, void* d_ws, size_t ws_size,
                              hipStream_t stream) {
    const float* x      = (const float*)d_in[0];
    const float* pre_W  = (const float*)d_in[1];
    const float* pre_b  = (const float*)d_in[2];
    const float* Wih_f  = (const float*)d_in[3];
    const float* Whh_f  = (const float*)d_in[4];
    const float* bih_f  = (const float*)d_in[5];
    const float* bhh_f  = (const float*)d_in[6];
    const float* Wih_r  = (const float*)d_in[7];
    const float* Whh_r  = (const float*)d_in[8];
    const float* bih_r  = (const float*)d_in[9];
    const float* bhh_r  = (const float*)d_in[10];
    const float* proj_W = (const float*)d_in[11];
    const float* proj_b = (const float*)d_in[12];
    float* out = (float*)d_out;

    uint16_t* xp = (uint16_t*)d_ws;                 // [NT][768]  bf16 (19.3 MB)
    uint16_t* y  = xp + (size_t)NT_ * D_;           // [NT][1536] bf16 (38.5 MB)

    dim3 g1(NT_ / 64, D_ / 64);
    gemm_nt_bf16out<768><<<g1, 256, 0, stream>>>(x, pre_W, pre_b, xp, D_);

    lstm_rec<<<192, 256, 0, stream>>>(xp, Wih_f, Whh_f, bih_f, bhh_f,
                                      Wih_r, Whh_r, bih_r, bhh_r, y);

    dim3 g3(NT_ / 64, D_ / 64);
    gemm_nt_bf16in_f32out<1536><<<g3, 256, 0, stream>>>(y, proj_W, proj_b, out, D_);
}

// Round 3
// 1652.188 us; speedup vs baseline: 1.5936x; 1.5936x over previous
//
#include <hip/hip_runtime.h>
#include <hip/hip_bf16.h>
#include <cstdint>
#include <cstddef>

#define B_   64
#define T_   196
#define D_   768
#define H_   12
#define HID_ 64
#define NT_  (B_ * T_)   // 12544

__device__ __forceinline__ float bf2f(uint16_t u) {
    uint32_t x = ((uint32_t)u) << 16;
    return __builtin_bit_cast(float, x);
}
__device__ __forceinline__ uint16_t f2bf(float f) {
    uint32_t x = __builtin_bit_cast(uint32_t, f);
    uint32_t r = (x + 0x7fffu + ((x >> 16) & 1u)) >> 16;
    return (uint16_t)r;
}

// ---------------------------------------------------------------------------
// K1: C_bf16[n][m] = sum_k A[n][k] * Bw[m][k] + bias[m]
//     A: [N][K] f32 row-major, Bw: [M][K] f32 row-major (NT gemm, K contiguous)
// grid: (N/64, M/64), block 256, 4x4 per thread
// ---------------------------------------------------------------------------
template<int KDIM>
__global__ __launch_bounds__(256)
void gemm_nt_bf16out(const float* __restrict__ A, const float* __restrict__ Bw,
                     const float* __restrict__ bias, uint16_t* __restrict__ C,
                     int Mtot)
{
    __shared__ float As[16][68];
    __shared__ float Bs[16][68];
    const int tid = threadIdx.x;
    const int n0 = blockIdx.x * 64, m0 = blockIdx.y * 64;
    const int lr = tid >> 2;          // 0..63
    const int lk = (tid & 3) << 2;    // 0,4,8,12
    const int tx = tid & 15, ty = tid >> 4;

    float acc[4][4];
#pragma unroll
    for (int i = 0; i < 4; i++)
#pragma unroll
        for (int jj = 0; jj < 4; jj++) acc[i][jj] = 0.f;

    const float* Ap = A + (size_t)(n0 + lr) * KDIM + lk;
    const float* Bp = Bw + (size_t)(m0 + lr) * KDIM + lk;

    for (int k0 = 0; k0 < KDIM; k0 += 16) {
        float4 av = *(const float4*)(Ap + k0);
        float4 bv = *(const float4*)(Bp + k0);
        As[lk + 0][lr] = av.x; As[lk + 1][lr] = av.y;
        As[lk + 2][lr] = av.z; As[lk + 3][lr] = av.w;
        Bs[lk + 0][lr] = bv.x; Bs[lk + 1][lr] = bv.y;
        Bs[lk + 2][lr] = bv.z; Bs[lk + 3][lr] = bv.w;
        __syncthreads();
#pragma unroll
        for (int k = 0; k < 16; k++) {
            float4 a = *(const float4*)&As[k][ty * 4];
            float4 b = *(const float4*)&Bs[k][tx * 4];
            float a4[4] = {a.x, a.y, a.z, a.w};
            float b4[4] = {b.x, b.y, b.z, b.w};
#pragma unroll
            for (int i = 0; i < 4; i++)
#pragma unroll
                for (int jj = 0; jj < 4; jj++) acc[i][jj] += a4[i] * b4[jj];
        }
        __syncthreads();
    }
#pragma unroll
    for (int i = 0; i < 4; i++) {
        const int n = n0 + ty * 4 + i;
#pragma unroll
        for (int jj = 0; jj < 4; jj++) {
            const int m = m0 + tx * 4 + jj;
            C[(size_t)n * Mtot + m] = f2bf(acc[i][jj] + bias[m]);
        }
    }
}

// ---------------------------------------------------------------------------
// K3: C_f32[n][m] = sum_k bf2f(A[n][k]) * Bw[m][k] + bias[m]
// ---------------------------------------------------------------------------
template<int KDIM>
__global__ __launch_bounds__(256)
void gemm_nt_bf16in_f32out(const uint16_t* __restrict__ A, const float* __restrict__ Bw,
                           const float* __restrict__ bias, float* __restrict__ C,
                           int Mtot)
{
    __shared__ float As[16][68];
    __shared__ float Bs[16][68];
    const int tid = threadIdx.x;
    const int n0 = blockIdx.x * 64, m0 = blockIdx.y * 64;
    const int lr = tid >> 2;
    const int lk = (tid & 3) << 2;
    const int tx = tid & 15, ty = tid >> 4;

    float acc[4][4];
#pragma unroll
    for (int i = 0; i < 4; i++)
#pragma unroll
        for (int jj = 0; jj < 4; jj++) acc[i][jj] = 0.f;

    const uint16_t* Ap = A + (size_t)(n0 + lr) * KDIM + lk;
    const float* Bp = Bw + (size_t)(m0 + lr) * KDIM + lk;

    for (int k0 = 0; k0 < KDIM; k0 += 16) {
        uint2 au = *(const uint2*)(Ap + k0);   // 4 bf16
        float4 bv = *(const float4*)(Bp + k0);
        As[lk + 0][lr] = bf2f((uint16_t)(au.x & 0xffffu));
        As[lk + 1][lr] = bf2f((uint16_t)(au.x >> 16));
        As[lk + 2][lr] = bf2f((uint16_t)(au.y & 0xffffu));
        As[lk + 3][lr] = bf2f((uint16_t)(au.y >> 16));
        Bs[lk + 0][lr] = bv.x; Bs[lk + 1][lr] = bv.y;
        Bs[lk + 2][lr] = bv.z; Bs[lk + 3][lr] = bv.w;
        __syncthreads();
#pragma unroll
        for (int k = 0; k < 16; k++) {
            float4 a = *(const float4*)&As[k][ty * 4];
            float4 b = *(const float4*)&Bs[k][tx * 4];
            float a4[4] = {a.x, a.y, a.z, a.w};
            float b4[4] = {b.x, b.y, b.z, b.w};
#pragma unroll
            for (int i = 0; i < 4; i++)
#pragma unroll
                for (int jj = 0; jj < 4; jj++) acc[i][jj] += a4[i] * b4[jj];
        }
        __syncthreads();
    }
#pragma unroll
    for (int i = 0; i < 4; i++) {
        const int n = n0 + ty * 4 + i;
#pragma unroll
        for (int jj = 0; jj < 4; jj++) {
            const int m = m0 + tx * 4 + jj;
            C[(size_t)n * Mtot + m] = acc[i][jj] + bias[m];
        }
    }
}

// ---------------------------------------------------------------------------
// K2: per-head bidirectional LSTM recurrence.
// grid = 24 chains (head,dir) x 8 batch-tiles of 8  = 192 blocks, 256 threads.
// Thread g owns gate row g. Weights held in 32 NAMED float4 variables (no
// alloca -> nothing for SROA to demote) + amdgpu_waves_per_eu(1) grants the
// full VGPR budget. R1/R2 showed VGPR_Count=84 (weights in scratch, 11x over
// the VALU floor); launch_bounds' 2nd arg did not change the budget.
// ---------------------------------------------------------------------------
__global__ __attribute__((amdgpu_waves_per_eu(1))) __launch_bounds__(256)
void lstm_rec(const uint16_t* __restrict__ xp,         // [NT][768] bf16
              const float* __restrict__ Wih_f, const float* __restrict__ Whh_f,
              const float* __restrict__ bih_f, const float* __restrict__ bhh_f,
              const float* __restrict__ Wih_r, const float* __restrict__ Whh_r,
              const float* __restrict__ bih_r, const float* __restrict__ bhh_r,
              uint16_t* __restrict__ y)                // [NT][1536] bf16
{
    const int blk   = blockIdx.x;
    const int btile = blk & 7;
    const int chain = blk >> 3;        // 0..23
    const int head  = chain % H_;
    const int dir   = chain / H_;
    const int b0    = btile * 8;
    const int g     = threadIdx.x;     // 0..255

    const float* Wih = dir ? Wih_r : Wih_f;
    const float* Whh = dir ? Whh_r : Whh_f;
    const float* bih = dir ? bih_r : bih_f;
    const float* bhh = dir ? bhh_r : bhh_f;

    __shared__ float xs[512];     // [8][64]
    __shared__ float hs[512];     // [8][64]
    __shared__ float Gs[2048];    // [8][256]

    const float4* wip4 = (const float4*)(Wih + ((size_t)head * 256 + g) * 64);
    const float4* whp4 = (const float4*)(Whh + ((size_t)head * 256 + g) * 64);

#define WDECL(i) float4 wi##i = wip4[i]; float4 wh##i = whp4[i];
    WDECL(0)  WDECL(1)  WDECL(2)  WDECL(3)
    WDECL(4)  WDECL(5)  WDECL(6)  WDECL(7)
    WDECL(8)  WDECL(9)  WDECL(10) WDECL(11)
    WDECL(12) WDECL(13) WDECL(14) WDECL(15)
#undef WDECL

    const float biasg = bih[head * 256 + g] + bhh[head * 256 + g];

    const int j  = g & 63;
    const int bq = g >> 6;
    float c0 = 0.f, c1 = 0.f;

    // init h = 0, prefetch x slice for t=0
    hs[g] = 0.f; hs[g + 256] = 0.f;
    {
        const int tt0 = dir ? (T_ - 1) : 0;
        const int idx = g * 2;
        const int bb = idx >> 6, dd = idx & 63;
        const uint16_t* xr = xp + ((size_t)(b0 + bb) * T_ + tt0) * D_ + head * 64 + dd;
        xs[idx] = bf2f(xr[0]); xs[idx + 1] = bf2f(xr[1]);
    }
    __syncthreads();

    for (int s = 0; s < T_; ++s) {
        const int tt = dir ? (T_ - 1 - s) : s;

        float acc[8];
#pragma unroll
        for (int b = 0; b < 8; b++) {
            const float4* xb = (const float4*)&xs[b * 64];
            const float4* hb = (const float4*)&hs[b * 64];
            float a = biasg;
#define STEP(i) { float4 xv = xb[i];                                          \
                  a += xv.x * wi##i.x + xv.y * wi##i.y +                      \
                       xv.z * wi##i.z + xv.w * wi##i.w;                       \
                  float4 hv = hb[i];                                          \
                  a += hv.x * wh##i.x + hv.y * wh##i.y +                      \
                       hv.z * wh##i.z + hv.w * wh##i.w; }
            STEP(0)  STEP(1)  STEP(2)  STEP(3)
            STEP(4)  STEP(5)  STEP(6)  STEP(7)
            STEP(8)  STEP(9)  STEP(10) STEP(11)
            STEP(12) STEP(13) STEP(14) STEP(15)
#undef STEP
            acc[b] = a;
        }
#pragma unroll
        for (int b = 0; b < 8; b++) Gs[b * 256 + g] = acc[b];
        __syncthreads();   // G ready; everyone done reading xs/hs

#pragma unroll
        for (int half = 0; half < 2; ++half) {
            const int b = bq + half * 4;
            const float gi = Gs[b * 256 + j];
            const float gf = Gs[b * 256 + 64 + j];
            const float gg = Gs[b * 256 + 128 + j];
            const float go = Gs[b * 256 + 192 + j];
            const float i_ = 1.f / (1.f + __expf(-gi));
            const float f_ = 1.f / (1.f + __expf(-gf));
            const float g_ = 1.f - 2.f / (1.f + __expf(2.f * gg));
            const float o_ = 1.f / (1.f + __expf(-go));
            float& c = half ? c1 : c0;
            c = f_ * c + i_ * g_;
            const float h = o_ * (1.f - 2.f / (1.f + __expf(2.f * c)));
            hs[b * 64 + j] = h;
            y[((size_t)(b0 + b) * T_ + tt) * 1536 + dir * 768 + head * 64 + j] = f2bf(h);
        }
        if (s + 1 < T_) {
            const int tn = dir ? (T_ - 2 - s) : (s + 1);
            const int idx = g * 2;
            const int bb = idx >> 6, dd = idx & 63;
            const uint16_t* xr = xp + ((size_t)(b0 + bb) * T_ + tn) * D_ + head * 64 + dd;
            xs[idx] = bf2f(xr[0]); xs[idx + 1] = bf2f(xr[1]);
        }
        __syncthreads();   // hs / xs ready for next step
    }
}

// ---------------------------------------------------------------------------
extern "C" void kernel_launch(void* const* d_in, const int* in_sizes, int n_in,
                              void* d_out, int out_size, void* d_ws, size_t ws_size,
                              hipStream_t stream) {
    const float* x      = (const float*)d_in[0];
    const float* pre_W  = (const float*)d_in[1];
    const float* pre_b  = (const float*)d_in[2];
    const float* Wih_f  = (const float*)d_in[3];
    const float* Whh_f  = (const float*)d_in[4];
    const float* bih_f  = (const float*)d_in[5];
    const float* bhh_f  = (const float*)d_in[6];
    const float* Wih_r  = (const float*)d_in[7];
    const float* Whh_r  = (const float*)d_in[8];
    const float* bih_r  = (const float*)d_in[9];
    const float* bhh_r  = (const float*)d_in[10];
    const float* proj_W = (const float*)d_in[11];
    const float* proj_b = (const float*)d_in[12];
    float* out = (float*)d_out;

    uint16_t* xp = (uint16_t*)d_ws;                 // [NT][768]  bf16 (19.3 MB)
    uint16_t* y  = xp + (size_t)NT_ * D_;           // [NT][1536] bf16 (38.5 MB)

    dim3 g1(NT_ / 64, D_ / 64);
    gemm_nt_bf16out<768><<<g1, 256, 0, stream>>>(x, pre_W, pre_b, xp, D_);

    lstm_rec<<<192, 256, 0, stream>>>(xp, Wih_f, Whh_f, bih_f, bhh_f,
                                      Wih_r, Whh_r, bih_r, bhh_r, y);

    dim3 g3(NT_ / 64, D_ / 64);
    gemm_nt_bf16in_f32out<1536><<<g3, 256, 0, stream>>>(y, proj_W, proj_b, out, D_);
}

// Round 4
// 1240.166 us; speedup vs baseline: 2.1231x; 1.3322x over previous
//
#include <hip/hip_runtime.h>
#include <hip/hip_bf16.h>
#include <cstdint>
#include <cstddef>

#define B_   64
#define T_   196
#define D_   768
#define H_   12
#define HID_ 64
#define NT_  (B_ * T_)   // 12544

typedef __attribute__((ext_vector_type(8))) __bf16 bf16x8;
typedef __attribute__((ext_vector_type(4))) float  f32x4;

__device__ __forceinline__ float bf2f(uint16_t u) {
    uint32_t x = ((uint32_t)u) << 16;
    return __builtin_bit_cast(float, x);
}
__device__ __forceinline__ uint16_t f2bf(float f) {
    uint32_t x = __builtin_bit_cast(uint32_t, f);
    uint32_t r = (x + 0x7fffu + ((x >> 16) & 1u)) >> 16;
    return (uint16_t)r;
}
__device__ __forceinline__ __bf16 f2bfv(float f) {
    return __builtin_bit_cast(__bf16, f2bf(f));
}
// XOR swizzle for [row][128] bf16 LDS tiles (row stride 256B): spreads the
// 16-lane same-column reads across 8 banks. Returns uint16 element index.
__device__ __forceinline__ int swz16(int row, int col) {
    int byte = (row << 8) + (col << 1);
    byte ^= (row & 7) << 4;
    return byte >> 1;
}

// ---------------------------------------------------------------------------
// K1: C_bf16[n][m] = sum_k A[n][k] * Bw[m][k] + bias[m]   (fp32 VALU, as R3)
// ---------------------------------------------------------------------------
template<int KDIM>
__global__ __launch_bounds__(256)
void gemm_nt_bf16out(const float* __restrict__ A, const float* __restrict__ Bw,
                     const float* __restrict__ bias, uint16_t* __restrict__ C,
                     int Mtot)
{
    __shared__ float As[16][68];
    __shared__ float Bs[16][68];
    const int tid = threadIdx.x;
    const int n0 = blockIdx.x * 64, m0 = blockIdx.y * 64;
    const int lr = tid >> 2;
    const int lk = (tid & 3) << 2;
    const int tx = tid & 15, ty = tid >> 4;

    float acc[4][4];
#pragma unroll
    for (int i = 0; i < 4; i++)
#pragma unroll
        for (int jj = 0; jj < 4; jj++) acc[i][jj] = 0.f;

    const float* Ap = A + (size_t)(n0 + lr) * KDIM + lk;
    const float* Bp = Bw + (size_t)(m0 + lr) * KDIM + lk;

    for (int k0 = 0; k0 < KDIM; k0 += 16) {
        float4 av = *(const float4*)(Ap + k0);
        float4 bv = *(const float4*)(Bp + k0);
        As[lk + 0][lr] = av.x; As[lk + 1][lr] = av.y;
        As[lk + 2][lr] = av.z; As[lk + 3][lr] = av.w;
        Bs[lk + 0][lr] = bv.x; Bs[lk + 1][lr] = bv.y;
        Bs[lk + 2][lr] = bv.z; Bs[lk + 3][lr] = bv.w;
        __syncthreads();
#pragma unroll
        for (int k = 0; k < 16; k++) {
            float4 a = *(const float4*)&As[k][ty * 4];
            float4 b = *(const float4*)&Bs[k][tx * 4];
            float a4[4] = {a.x, a.y, a.z, a.w};
            float b4[4] = {b.x, b.y, b.z, b.w};
#pragma unroll
            for (int i = 0; i < 4; i++)
#pragma unroll
                for (int jj = 0; jj < 4; jj++) acc[i][jj] += a4[i] * b4[jj];
        }
        __syncthreads();
    }
#pragma unroll
    for (int i = 0; i < 4; i++) {
        const int n = n0 + ty * 4 + i;
#pragma unroll
        for (int jj = 0; jj < 4; jj++) {
            const int m = m0 + tx * 4 + jj;
            C[(size_t)n * Mtot + m] = f2bf(acc[i][jj] + bias[m]);
        }
    }
}

// ---------------------------------------------------------------------------
// K3: C_f32[n][m] = sum_k bf2f(A[n][k]) * Bw[m][k] + bias[m]
// ---------------------------------------------------------------------------
template<int KDIM>
__global__ __launch_bounds__(256)
void gemm_nt_bf16in_f32out(const uint16_t* __restrict__ A, const float* __restrict__ Bw,
                           const float* __restrict__ bias, float* __restrict__ C,
                           int Mtot)
{
    __shared__ float As[16][68];
    __shared__ float Bs[16][68];
    const int tid = threadIdx.x;
    const int n0 = blockIdx.x * 64, m0 = blockIdx.y * 64;
    const int lr = tid >> 2;
    const int lk = (tid & 3) << 2;
    const int tx = tid & 15, ty = tid >> 4;

    float acc[4][4];
#pragma unroll
    for (int i = 0; i < 4; i++)
#pragma unroll
        for (int jj = 0; jj < 4; jj++) acc[i][jj] = 0.f;

    const uint16_t* Ap = A + (size_t)(n0 + lr) * KDIM + lk;
    const float* Bp = Bw + (size_t)(m0 + lr) * KDIM + lk;

    for (int k0 = 0; k0 < KDIM; k0 += 16) {
        uint2 au = *(const uint2*)(Ap + k0);
        float4 bv = *(const float4*)(Bp + k0);
        As[lk + 0][lr] = bf2f((uint16_t)(au.x & 0xffffu));
        As[lk + 1][lr] = bf2f((uint16_t)(au.x >> 16));
        As[lk + 2][lr] = bf2f((uint16_t)(au.y & 0xffffu));
        As[lk + 3][lr] = bf2f((uint16_t)(au.y >> 16));
        Bs[lk + 0][lr] = bv.x; Bs[lk + 1][lr] = bv.y;
        Bs[lk + 2][lr] = bv.z; Bs[lk + 3][lr] = bv.w;
        __syncthreads();
#pragma unroll
        for (int k = 0; k < 16; k++) {
            float4 a = *(const float4*)&As[k][ty * 4];
            float4 b = *(const float4*)&Bs[k][tx * 4];
            float a4[4] = {a.x, a.y, a.z, a.w};
            float b4[4] = {b.x, b.y, b.z, b.w};
#pragma unroll
            for (int i = 0; i < 4; i++)
#pragma unroll
                for (int jj = 0; jj < 4; jj++) acc[i][jj] += a4[i] * b4[jj];
        }
        __syncthreads();
    }
#pragma unroll
    for (int i = 0; i < 4; i++) {
        const int n = n0 + ty * 4 + i;
#pragma unroll
        for (int jj = 0; jj < 4; jj++) {
            const int m = m0 + tx * 4 + jj;
            C[(size_t)n * Mtot + m] = acc[i][jj] + bias[m];
        }
    }
}

// ---------------------------------------------------------------------------
// K2 (MFMA): one block per (head,dir) chain, 512 threads = 8 waves.
// Per step computes G^T[256 gates][64 batch] = Wc[256][128] . Act^T[128][64]
// with mfma_f32_16x16x32_bf16. Wave w: q = w>>1 (hid group 16q..),
// bhalf = w&1 (batches 32*bhalf..+32 as 2 col-tiles).
// D-layout (m89): col=lane&15 -> batch, row=(lane>>4)*4+reg -> gate row, so
// i/f/g/o of one (batch,hid) land in the SAME lane+reg across the 4 gate-tile
// accumulators: cell update is pure in-register.
// W fragments preloaded to 64 VGPRs once (asm-pinned vs rematerialization).
// Act[64][128] bf16 in LDS, XOR-swizzled (T2) for conflict-free ds_read_b128.
// ---------------------------------------------------------------------------
__global__ __launch_bounds__(512) __attribute__((amdgpu_waves_per_eu(2, 2)))
void lstm_rec_mfma(const uint16_t* __restrict__ xp,     // [NT][768] bf16
                   const float* __restrict__ Wih_f, const float* __restrict__ Whh_f,
                   const float* __restrict__ bih_f, const float* __restrict__ bhh_f,
                   const float* __restrict__ Wih_r, const float* __restrict__ Whh_r,
                   const float* __restrict__ bih_r, const float* __restrict__ bhh_r,
                   uint16_t* __restrict__ y)            // [NT][1536] bf16
{
    const int chain = blockIdx.x;       // 0..23
    const int head  = chain % H_;
    const int dir   = chain / H_;
    const int tid   = threadIdx.x;      // 0..511
    const int lane  = tid & 63;
    const int wave  = tid >> 6;         // 0..7
    const int q     = wave >> 1;        // hid group
    const int bhalf = wave & 1;         // batch half

    const float* WihP = (dir ? Wih_r : Wih_f) + (size_t)head * 256 * 64;
    const float* WhhP = (dir ? Whh_r : Whh_f) + (size_t)head * 256 * 64;
    const float* bihP = (dir ? bih_r : bih_f) + head * 256;
    const float* bhhP = (dir ? bhh_r : bhh_f) + head * 256;

    __shared__ uint16_t Act[64 * 128];  // [batch][x(0:64)|h(64:128)] bf16, swizzled

    const int fr = lane & 15;           // frag row (tile-local)
    const int fk = (lane >> 4) << 3;    // k sub-offset 0,8,16,24

    // ---- preload W fragments (A-operand): wfrag[gate][kk] ----
    bf16x8 wfrag[4][4];
#pragma unroll
    for (int gi = 0; gi < 4; ++gi) {
        const int row = 16 * q + 64 * gi + fr;
#pragma unroll
        for (int kk = 0; kk < 4; ++kk) {
            const int k0 = 32 * kk + fk;
            const float* src = (k0 < 64) ? (WihP + row * 64 + k0)
                                         : (WhhP + row * 64 + (k0 - 64));
            float4 aa = *(const float4*)(src);
            float4 bb = *(const float4*)(src + 4);
            bf16x8 w;
            w[0] = f2bfv(aa.x); w[1] = f2bfv(aa.y); w[2] = f2bfv(aa.z); w[3] = f2bfv(aa.w);
            w[4] = f2bfv(bb.x); w[5] = f2bfv(bb.y); w[6] = f2bfv(bb.z); w[7] = f2bfv(bb.w);
            wfrag[gi][kk] = w;
        }
    }
#pragma unroll
    for (int gi = 0; gi < 4; ++gi)
#pragma unroll
        for (int kk = 0; kk < 4; ++kk)
            asm volatile("" : "+v"(wfrag[gi][kk]));   // pin: no remat/reload

    // ---- per-lane bias (acc init): binit[gate][r], r -> gate row (lane>>4)*4+r
    f32x4 binit[4];
#pragma unroll
    for (int gi = 0; gi < 4; ++gi) {
#pragma unroll
        for (int r = 0; r < 4; ++r) {
            const int row = 16 * q + 64 * gi + (lane >> 4) * 4 + r;
            binit[gi][r] = bihP[row] + bhhP[row];
        }
    }

    // ---- init: h part = 0; x part = x(t0) ----
    for (int idx = tid; idx < 64 * 64; idx += 512) {
        const int row = idx >> 6, col = idx & 63;
        Act[swz16(row, 64 + col)] = 0;
    }
    {
        const int batch = tid >> 3, d0 = (tid & 7) * 8;
        const int t0 = dir ? (T_ - 1) : 0;
        uint4 v = *(const uint4*)(xp + ((size_t)batch * T_ + t0) * D_ + head * 64 + d0);
        *(uint4*)&Act[swz16(batch, d0)] = v;
    }
    __syncthreads();

    float cst[2][4] = {{0.f, 0.f, 0.f, 0.f}, {0.f, 0.f, 0.f, 0.f}};

    for (int s = 0; s < T_; ++s) {
        const int tt = dir ? (T_ - 1 - s) : s;

        // (a) stage next x tile into regs (latency hides under MFMA+gates)
        uint4 xstage = {0, 0, 0, 0};
        const int batch = tid >> 3, d0 = (tid & 7) * 8;
        if (s + 1 < T_) {
            const int tn = dir ? (T_ - 2 - s) : (s + 1);
            xstage = *(const uint4*)(xp + ((size_t)batch * T_ + tn) * D_ + head * 64 + d0);
        }

        // (b) MFMA: acc[gate][ct] over K=128
        f32x4 acc[4][2];
#pragma unroll
        for (int gi = 0; gi < 4; ++gi) {
            acc[gi][0] = binit[gi];
            acc[gi][1] = binit[gi];
        }
#pragma unroll
        for (int kk = 0; kk < 4; ++kk) {
            bf16x8 af0 = *(const bf16x8*)&Act[swz16(16 * (2 * bhalf + 0) + fr, 32 * kk + fk)];
            bf16x8 af1 = *(const bf16x8*)&Act[swz16(16 * (2 * bhalf + 1) + fr, 32 * kk + fk)];
#pragma unroll
            for (int gi = 0; gi < 4; ++gi) {
                acc[gi][0] = __builtin_amdgcn_mfma_f32_16x16x32_bf16(wfrag[gi][kk], af0, acc[gi][0], 0, 0, 0);
                acc[gi][1] = __builtin_amdgcn_mfma_f32_16x16x32_bf16(wfrag[gi][kk], af1, acc[gi][1], 0, 0, 0);
            }
        }

        // (c) gates + cell update, in-register
        ushort4 hpack[2];
#pragma unroll
        for (int ct = 0; ct < 2; ++ct) {
#pragma unroll
            for (int r = 0; r < 4; ++r) {
                const float vi = acc[0][ct][r];
                const float vf = acc[1][ct][r];
                const float vg = acc[2][ct][r];
                const float vo = acc[3][ct][r];
                const float i_ = 1.f / (1.f + __expf(-vi));
                const float f_ = 1.f / (1.f + __expf(-vf));
                const float g_ = 1.f - 2.f / (1.f + __expf(2.f * vg));
                const float o_ = 1.f / (1.f + __expf(-vo));
                const float c  = f_ * cst[ct][r] + i_ * g_;
                cst[ct][r] = c;
                const float h = o_ * (1.f - 2.f / (1.f + __expf(2.f * c)));
                ((unsigned short*)&hpack[ct])[r] = f2bf(h);
            }
        }

        __syncthreads();   // (d) everyone done reading Act(t)

        // (e) write h(t) (4 consecutive hids -> 8B) and x(t+1)
        {
            const int hcol = 64 + 16 * q + (lane >> 4) * 4;
#pragma unroll
            for (int ct = 0; ct < 2; ++ct) {
                const int hb = 16 * (2 * bhalf + ct) + fr;
                *(ushort4*)&Act[swz16(hb, hcol)] = hpack[ct];
            }
            if (s + 1 < T_) *(uint4*)&Act[swz16(batch, d0)] = xstage;
        }

        __syncthreads();   // (f) Act(t+1) ready

        // (g) coalesced y write: read back h block, 16B per thread
        {
            uint4 hv = *(const uint4*)&Act[swz16(batch, 64 + d0)];
            *(uint4*)(y + ((size_t)batch * T_ + tt) * 1536 + dir * 768 + head * 64 + d0) = hv;
        }
    }
}

// ---------------------------------------------------------------------------
extern "C" void kernel_launch(void* const* d_in, const int* in_sizes, int n_in,
                              void* d_out, int out_size, void* d_ws, size_t ws_size,
                              hipStream_t stream) {
    const float* x      = (const float*)d_in[0];
    const float* pre_W  = (const float*)d_in[1];
    const float* pre_b  = (const float*)d_in[2];
    const float* Wih_f  = (const float*)d_in[3];
    const float* Whh_f  = (const float*)d_in[4];
    const float* bih_f  = (const float*)d_in[5];
    const float* bhh_f  = (const float*)d_in[6];
    const float* Wih_r  = (const float*)d_in[7];
    const float* Whh_r  = (const float*)d_in[8];
    const float* bih_r  = (const float*)d_in[9];
    const float* bhh_r  = (const float*)d_in[10];
    const float* proj_W = (const float*)d_in[11];
    const float* proj_b = (const float*)d_in[12];
    float* out = (float*)d_out;

    uint16_t* xp = (uint16_t*)d_ws;                 // [NT][768]  bf16 (19.3 MB)
    uint16_t* y  = xp + (size_t)NT_ * D_;           // [NT][1536] bf16 (38.5 MB)

    dim3 g1(NT_ / 64, D_ / 64);
    gemm_nt_bf16out<768><<<g1, 256, 0, stream>>>(x, pre_W, pre_b, xp, D_);

    lstm_rec_mfma<<<24, 512, 0, stream>>>(xp, Wih_f, Whh_f, bih_f, bhh_f,
                                          Wih_r, Whh_r, bih_r, bhh_r, y);

    dim3 g3(NT_ / 64, D_ / 64);
    gemm_nt_bf16in_f32out<1536><<<g3, 256, 0, stream>>>(y, proj_W, proj_b, out, D_);
}

// Round 5
// 408.939 us; speedup vs baseline: 6.4386x; 3.0326x over previous
//
#include <hip/hip_runtime.h>
#include <hip/hip_bf16.h>
#include <cstdint>
#include <cstddef>

#define B_   64
#define T_   196
#define D_   768
#define H_   12
#define HID_ 64
#define NT_  (B_ * T_)   // 12544

typedef __attribute__((ext_vector_type(8))) __bf16 bf16x8;
typedef __attribute__((ext_vector_type(4))) float  f32x4;

__device__ __forceinline__ float bf2f(uint16_t u) {
    uint32_t x = ((uint32_t)u) << 16;
    return __builtin_bit_cast(float, x);
}
__device__ __forceinline__ uint16_t f2bf(float f) {
    uint32_t x = __builtin_bit_cast(uint32_t, f);
    uint32_t r = (x + 0x7fffu + ((x >> 16) & 1u)) >> 16;
    return (uint16_t)r;
}
__device__ __forceinline__ __bf16 f2bfv(float f) {
    return __builtin_bit_cast(__bf16, f2bf(f));
}

// XOR swizzle for [row][32] bf16 GEMM tiles (row stride 64B).
__device__ __forceinline__ int swzg(int row, int col) {
    int b = (row << 6) + (col << 1);
    b ^= (row & 7) << 4;
    return b >> 1;
}
// XOR swizzle for [row][128] bf16 Act tiles (row stride 256B).
__device__ __forceinline__ int swzA(int row, int col) {
    int b = (row << 8) + (col << 1);
    b ^= (row & 7) << 4;
    return b >> 1;
}

// ---------------------------------------------------------------------------
// f32 -> bf16 bulk convert (for pre_W / proj_W), float4 vectorized.
// ---------------------------------------------------------------------------
__global__ __launch_bounds__(256)
void f32_to_bf16_k(const float* __restrict__ in, uint16_t* __restrict__ out, int n4)
{
    int i = blockIdx.x * 256 + threadIdx.x;
    const int stride = gridDim.x * 256;
    for (; i < n4; i += stride) {
        float4 v = ((const float4*)in)[i];
        ushort4 o;
        o.x = f2bf(v.x); o.y = f2bf(v.y); o.z = f2bf(v.z); o.w = f2bf(v.w);
        ((ushort4*)out)[i] = o;
    }
}

// ---------------------------------------------------------------------------
// MFMA NT-GEMM: C[n][m] = sum_k A[n,k]*B[m,k] + bias[m]
// A: [N][KDIM] (f32 if A_F32 else bf16), B: [M][KDIM] bf16, C: [N][Mtot].
// 128x128 tile, 256 thr = 4 waves (wr=wv>>1, wc=wv&1), each 64x64 = 4x4 frags
// of 16x16x32. Double-buffered LDS [128][32] bf16, XOR-swizzled (swzg).
// Reg-staged: thread t loads row t>>1, 16 cols at 16*(t&1); ds_write_b128 x2.
// D layout (m89, verified in R4): col=lane&15 -> m, row=(lane>>4)*4+r -> n.
// ---------------------------------------------------------------------------
template<int KDIM, bool A_F32, bool OUT_BF16>
__global__ __launch_bounds__(256) __attribute__((amdgpu_waves_per_eu(2)))
void gemm_nt_mfma(const void* __restrict__ Aab, const uint16_t* __restrict__ Bw,
                  const float* __restrict__ bias, void* __restrict__ Cout, int Mtot)
{
    constexpr int NK = KDIM / 32;
    __shared__ uint16_t smA[2][128 * 32];
    __shared__ uint16_t smB[2][128 * 32];

    const int tid = threadIdx.x, lane = tid & 63, wv = tid >> 6;
    const int n0 = blockIdx.x * 128, m0 = blockIdx.y * 128;
    const int wr = wv >> 1, wc = wv & 1;
    const int fr = lane & 15;
    const int fk8 = (lane >> 4) * 8;

    const int srow = tid >> 1;
    const int scol = (tid & 1) * 16;

    const float*    Af = (const float*)Aab;
    const uint16_t* Ab = (const uint16_t*)Aab;

    f32x4 acc[4][4];
#pragma unroll
    for (int i = 0; i < 4; ++i)
#pragma unroll
        for (int j = 0; j < 4; ++j) acc[i][j] = (f32x4){0.f, 0.f, 0.f, 0.f};

    uint4 rA0, rA1, rB0, rB1;

    auto loadA = [&](int k0) {
        if constexpr (A_F32) {
            const float* p = Af + (size_t)(n0 + srow) * KDIM + k0 + scol;
            float4 a0 = *(const float4*)(p);
            float4 a1 = *(const float4*)(p + 4);
            float4 a2 = *(const float4*)(p + 8);
            float4 a3 = *(const float4*)(p + 12);
            rA0.x = (uint32_t)f2bf(a0.x) | ((uint32_t)f2bf(a0.y) << 16);
            rA0.y = (uint32_t)f2bf(a0.z) | ((uint32_t)f2bf(a0.w) << 16);
            rA0.z = (uint32_t)f2bf(a1.x) | ((uint32_t)f2bf(a1.y) << 16);
            rA0.w = (uint32_t)f2bf(a1.z) | ((uint32_t)f2bf(a1.w) << 16);
            rA1.x = (uint32_t)f2bf(a2.x) | ((uint32_t)f2bf(a2.y) << 16);
            rA1.y = (uint32_t)f2bf(a2.z) | ((uint32_t)f2bf(a2.w) << 16);
            rA1.z = (uint32_t)f2bf(a3.x) | ((uint32_t)f2bf(a3.y) << 16);
            rA1.w = (uint32_t)f2bf(a3.z) | ((uint32_t)f2bf(a3.w) << 16);
        } else {
            const uint16_t* p = Ab + (size_t)(n0 + srow) * KDIM + k0 + scol;
            rA0 = *(const uint4*)p;
            rA1 = *(const uint4*)(p + 8);
        }
    };
    auto loadB = [&](int k0) {
        const uint16_t* p = Bw + (size_t)(m0 + srow) * KDIM + k0 + scol;
        rB0 = *(const uint4*)p;
        rB1 = *(const uint4*)(p + 8);
    };
    auto dsWrite = [&](int buf) {
        *(uint4*)&smA[buf][swzg(srow, scol)]     = rA0;
        *(uint4*)&smA[buf][swzg(srow, scol + 8)] = rA1;
        *(uint4*)&smB[buf][swzg(srow, scol)]     = rB0;
        *(uint4*)&smB[buf][swzg(srow, scol + 8)] = rB1;
    };

    loadA(0); loadB(0);
    dsWrite(0);

    for (int kt = 0; kt < NK; ++kt) {
        __syncthreads();
        const int buf = kt & 1;
        const bool more = (kt + 1) < NK;
        if (more) { loadA(32 * (kt + 1)); loadB(32 * (kt + 1)); }

        bf16x8 af[4], bfg[4];
#pragma unroll
        for (int i = 0; i < 4; ++i)
            af[i] = *(const bf16x8*)&smA[buf][swzg(64 * wr + 16 * i + fr, fk8)];
#pragma unroll
        for (int j = 0; j < 4; ++j)
            bfg[j] = *(const bf16x8*)&smB[buf][swzg(64 * wc + 16 * j + fr, fk8)];
#pragma unroll
        for (int i = 0; i < 4; ++i)
#pragma unroll
            for (int j = 0; j < 4; ++j)
                acc[i][j] = __builtin_amdgcn_mfma_f32_16x16x32_bf16(af[i], bfg[j], acc[i][j], 0, 0, 0);

        if (more) dsWrite(buf ^ 1);
    }

    float biasj[4];
#pragma unroll
    for (int j = 0; j < 4; ++j) biasj[j] = bias[m0 + 64 * wc + 16 * j + fr];

#pragma unroll
    for (int i = 0; i < 4; ++i) {
#pragma unroll
        for (int r = 0; r < 4; ++r) {
            const int n = n0 + 64 * wr + 16 * i + (lane >> 4) * 4 + r;
#pragma unroll
            for (int j = 0; j < 4; ++j) {
                const int m = m0 + 64 * wc + 16 * j + fr;
                const float v = acc[i][j][r] + biasj[j];
                if constexpr (OUT_BF16)
                    ((uint16_t*)Cout)[(size_t)n * Mtot + m] = f2bf(v);
                else
                    ((float*)Cout)[(size_t)n * Mtot + m] = v;
            }
        }
    }
}

// ---------------------------------------------------------------------------
// K2 (MFMA): 96 blocks = 24 chains x 4 batch-tiles of 16. 256 thr = 4 waves.
// Wave q owns hid rows 16q+64gi (gi=0..3 -> i,f,g,o tiles); all 16 batches.
// Act[16][128] bf16 swizzled. Per step: 16 MFMA/wave, in-register cell update
// (D: col=lane&15 -> batch, row=(lane>>4)*4+r -> hid within tile).
// ---------------------------------------------------------------------------
__global__ __launch_bounds__(256) __attribute__((amdgpu_waves_per_eu(1, 1)))
void lstm_rec_mfma(const uint16_t* __restrict__ xp,     // [NT][768] bf16
                   const float* __restrict__ Wih_f, const float* __restrict__ Whh_f,
                   const float* __restrict__ bih_f, const float* __restrict__ bhh_f,
                   const float* __restrict__ Wih_r, const float* __restrict__ Whh_r,
                   const float* __restrict__ bih_r, const float* __restrict__ bhh_r,
                   uint16_t* __restrict__ y)            // [NT][1536] bf16
{
    const int blk   = blockIdx.x;        // 0..95
    const int b0    = (blk & 3) * 16;
    const int chain = blk >> 2;          // 0..23
    const int head  = chain % H_;
    const int dir   = chain / H_;
    const int tid   = threadIdx.x;       // 0..255
    const int lane  = tid & 63;
    const int q     = tid >> 6;          // wave = hid group 0..3

    const float* WihP = (dir ? Wih_r : Wih_f) + (size_t)head * 256 * 64;
    const float* WhhP = (dir ? Whh_r : Whh_f) + (size_t)head * 256 * 64;
    const float* bihP = (dir ? bih_r : bih_f) + head * 256;
    const float* bhhP = (dir ? bhh_r : bhh_f) + head * 256;

    __shared__ uint16_t Act[16 * 128];   // [batch 16][x(0:64)|h(64:128)], swizzled

    const int fr = lane & 15;
    const int fk = (lane >> 4) << 3;     // 0,8,16,24

    // ---- preload W fragments: wfrag[gi][kk] (64 VGPRs, pinned) ----
    bf16x8 wfrag[4][4];
#pragma unroll
    for (int gi = 0; gi < 4; ++gi) {
        const int row = 16 * q + 64 * gi + fr;
#pragma unroll
        for (int kk = 0; kk < 4; ++kk) {
            const int k0 = 32 * kk + fk;
            const float* src = (k0 < 64) ? (WihP + row * 64 + k0)
                                         : (WhhP + row * 64 + (k0 - 64));
            float4 aa = *(const float4*)(src);
            float4 bb = *(const float4*)(src + 4);
            bf16x8 w;
            w[0] = f2bfv(aa.x); w[1] = f2bfv(aa.y); w[2] = f2bfv(aa.z); w[3] = f2bfv(aa.w);
            w[4] = f2bfv(bb.x); w[5] = f2bfv(bb.y); w[6] = f2bfv(bb.z); w[7] = f2bfv(bb.w);
            wfrag[gi][kk] = w;
        }
    }
#pragma unroll
    for (int gi = 0; gi < 4; ++gi)
#pragma unroll
        for (int kk = 0; kk < 4; ++kk)
            asm volatile("" : "+v"(wfrag[gi][kk]));

    f32x4 binit[4];
#pragma unroll
    for (int gi = 0; gi < 4; ++gi) {
#pragma unroll
        for (int r = 0; r < 4; ++r) {
            const int row = 16 * q + 64 * gi + (lane >> 4) * 4 + r;
            binit[gi][r] = bihP[row] + bhhP[row];
        }
    }

    // ---- init Act: h = 0, x = x(t0). thread t: batch=t>>4, d0=(t&15)*4 ----
    const int batch = tid >> 4;
    const int d0    = (tid & 15) * 4;
    {
        uint2 z; z.x = 0; z.y = 0;
        *(uint2*)&Act[swzA(batch, 64 + d0)] = z;
        const int t0 = dir ? (T_ - 1) : 0;
        uint2 xv = *(const uint2*)(xp + ((size_t)(b0 + batch) * T_ + t0) * D_ + head * 64 + d0);
        *(uint2*)&Act[swzA(batch, d0)] = xv;
    }
    __syncthreads();

    float cst[4] = {0.f, 0.f, 0.f, 0.f};

    for (int s = 0; s < T_; ++s) {
        const int tt = dir ? (T_ - 1 - s) : s;

        // (a) prefetch next x into regs
        uint2 xstage; xstage.x = 0; xstage.y = 0;
        if (s + 1 < T_) {
            const int tn = dir ? (T_ - 2 - s) : (s + 1);
            xstage = *(const uint2*)(xp + ((size_t)(b0 + batch) * T_ + tn) * D_ + head * 64 + d0);
        }

        // (b) MFMA over K=128
        f32x4 acc[4];
#pragma unroll
        for (int gi = 0; gi < 4; ++gi) acc[gi] = binit[gi];
#pragma unroll
        for (int kk = 0; kk < 4; ++kk) {
            bf16x8 afr = *(const bf16x8*)&Act[swzA(fr, 32 * kk + fk)];
#pragma unroll
            for (int gi = 0; gi < 4; ++gi)
                acc[gi] = __builtin_amdgcn_mfma_f32_16x16x32_bf16(wfrag[gi][kk], afr, acc[gi], 0, 0, 0);
        }

        // (c) gates + cell update (lane: batch=fr? no -> batch=lane&15 via D col)
        ushort4 hpack;
#pragma unroll
        for (int r = 0; r < 4; ++r) {
            const float vi = acc[0][r];
            const float vf = acc[1][r];
            const float vg = acc[2][r];
            const float vo = acc[3][r];
            const float i_ = 1.f / (1.f + __expf(-vi));
            const float f_ = 1.f / (1.f + __expf(-vf));
            const float g_ = 1.f - 2.f / (1.f + __expf(2.f * vg));
            const float o_ = 1.f / (1.f + __expf(-vo));
            const float c  = f_ * cst[r] + i_ * g_;
            cst[r] = c;
            const float h = o_ * (1.f - 2.f / (1.f + __expf(2.f * c)));
            ((unsigned short*)&hpack)[r] = f2bf(h);
        }

        __syncthreads();   // all reads of Act(t) done

        // (d) write h(t): lane's batch = lane&15 = fr, hid col = 16q+(lane>>4)*4
        *(ushort4*)&Act[swzA(fr, 64 + 16 * q + (lane >> 4) * 4)] = hpack;
        if (s + 1 < T_) *(uint2*)&Act[swzA(batch, d0)] = xstage;

        __syncthreads();   // Act(t+1) ready

        // (e) coalesced y write via readback
        uint2 hv = *(const uint2*)&Act[swzA(batch, 64 + d0)];
        *(uint2*)(y + ((size_t)(b0 + batch) * T_ + tt) * 1536 + dir * 768 + head * 64 + d0) = hv;
    }
}

// ---------------------------------------------------------------------------
extern "C" void kernel_launch(void* const* d_in, const int* in_sizes, int n_in,
                              void* d_out, int out_size, void* d_ws, size_t ws_size,
                              hipStream_t stream) {
    const float* x      = (const float*)d_in[0];
    const float* pre_W  = (const float*)d_in[1];
    const float* pre_b  = (const float*)d_in[2];
    const float* Wih_f  = (const float*)d_in[3];
    const float* Whh_f  = (const float*)d_in[4];
    const float* bih_f  = (const float*)d_in[5];
    const float* bhh_f  = (const float*)d_in[6];
    const float* Wih_r  = (const float*)d_in[7];
    const float* Whh_r  = (const float*)d_in[8];
    const float* bih_r  = (const float*)d_in[9];
    const float* bhh_r  = (const float*)d_in[10];
    const float* proj_W = (const float*)d_in[11];
    const float* proj_b = (const float*)d_in[12];
    float* out = (float*)d_out;

    uint16_t* xp      = (uint16_t*)d_ws;                  // [NT][768]  19.3 MB
    uint16_t* y       = xp + (size_t)NT_ * D_;            // [NT][1536] 38.5 MB
    uint16_t* preWbf  = y + (size_t)NT_ * 1536;           // 768*768    1.2 MB
    uint16_t* projWbf = preWbf + (size_t)D_ * D_;         // 768*1536   2.4 MB

    f32_to_bf16_k<<<256, 256, 0, stream>>>(pre_W, preWbf, D_ * D_ / 4);
    f32_to_bf16_k<<<256, 256, 0, stream>>>(proj_W, projWbf, D_ * 1536 / 4);

    dim3 g1(NT_ / 128, D_ / 128);   // (98, 6)
    gemm_nt_mfma<768, true, true><<<g1, 256, 0, stream>>>(x, preWbf, pre_b, xp, D_);

    lstm_rec_mfma<<<96, 256, 0, stream>>>(xp, Wih_f, Whh_f, bih_f, bhh_f,
                                          Wih_r, Whh_r, bih_r, bhh_r, y);

    dim3 g3(NT_ / 128, D_ / 128);   // (98, 6)
    gemm_nt_mfma<1536, false, false><<<g3, 256, 0, stream>>>(y, projWbf, proj_b, out, D_);
}

// Round 6
// 329.314 us; speedup vs baseline: 7.9954x; 1.2418x over previous
//
#include <hip/hip_runtime.h>
#include <hip/hip_bf16.h>
#include <cstdint>
#include <cstddef>

#define B_   64
#define T_   196
#define D_   768
#define H_   12
#define HID_ 64
#define NT_  (B_ * T_)   // 12544

typedef __attribute__((ext_vector_type(8))) __bf16 bf16x8;
typedef __attribute__((ext_vector_type(4))) float  f32x4;

__device__ __forceinline__ float bf2f(uint16_t u) {
    uint32_t x = ((uint32_t)u) << 16;
    return __builtin_bit_cast(float, x);
}
__device__ __forceinline__ uint16_t f2bf(float f) {
    uint32_t x = __builtin_bit_cast(uint32_t, f);
    uint32_t r = (x + 0x7fffu + ((x >> 16) & 1u)) >> 16;
    return (uint16_t)r;
}
__device__ __forceinline__ __bf16 f2bfv(float f) {
    return __builtin_bit_cast(__bf16, f2bf(f));
}

// fast gate math: v_rcp_f32 (~1 ulp) instead of IEEE div expansion (~9 instrs)
__device__ __forceinline__ float sigm(float x) {
    return __builtin_amdgcn_rcpf(1.f + __expf(-x));
}
__device__ __forceinline__ float tanh_f(float x) {
    return 1.f - 2.f * __builtin_amdgcn_rcpf(1.f + __expf(2.f * x));
}

// XOR swizzle for [row][32] bf16 GEMM tiles (row stride 64B).
__device__ __forceinline__ int swzg(int row, int col) {
    int b = (row << 6) + (col << 1);
    b ^= (row & 7) << 4;
    return b >> 1;
}
// XOR swizzle for [row][128] bf16 Act tiles (row stride 256B).
__device__ __forceinline__ int swzA(int row, int col) {
    int b = (row << 8) + (col << 1);
    b ^= (row & 7) << 4;
    return b >> 1;
}

// ---------------------------------------------------------------------------
// f32 -> bf16 bulk convert (for pre_W / proj_W), float4 vectorized.
// ---------------------------------------------------------------------------
__global__ __launch_bounds__(256)
void f32_to_bf16_k(const float* __restrict__ in, uint16_t* __restrict__ out, int n4)
{
    int i = blockIdx.x * 256 + threadIdx.x;
    const int stride = gridDim.x * 256;
    for (; i < n4; i += stride) {
        float4 v = ((const float4*)in)[i];
        ushort4 o;
        o.x = f2bf(v.x); o.y = f2bf(v.y); o.z = f2bf(v.z); o.w = f2bf(v.w);
        ((ushort4*)out)[i] = o;
    }
}

// ---------------------------------------------------------------------------
// MFMA NT-GEMM: C[n][m] = sum_k A[n,k]*B[m,k] + bias[m]   (unchanged from R5)
// ---------------------------------------------------------------------------
template<int KDIM, bool A_F32, bool OUT_BF16>
__global__ __launch_bounds__(256) __attribute__((amdgpu_waves_per_eu(2)))
void gemm_nt_mfma(const void* __restrict__ Aab, const uint16_t* __restrict__ Bw,
                  const float* __restrict__ bias, void* __restrict__ Cout, int Mtot)
{
    constexpr int NK = KDIM / 32;
    __shared__ uint16_t smA[2][128 * 32];
    __shared__ uint16_t smB[2][128 * 32];

    const int tid = threadIdx.x, lane = tid & 63, wv = tid >> 6;
    const int n0 = blockIdx.x * 128, m0 = blockIdx.y * 128;
    const int wr = wv >> 1, wc = wv & 1;
    const int fr = lane & 15;
    const int fk8 = (lane >> 4) * 8;

    const int srow = tid >> 1;
    const int scol = (tid & 1) * 16;

    const float*    Af = (const float*)Aab;
    const uint16_t* Ab = (const uint16_t*)Aab;

    f32x4 acc[4][4];
#pragma unroll
    for (int i = 0; i < 4; ++i)
#pragma unroll
        for (int j = 0; j < 4; ++j) acc[i][j] = (f32x4){0.f, 0.f, 0.f, 0.f};

    uint4 rA0, rA1, rB0, rB1;

    auto loadA = [&](int k0) {
        if constexpr (A_F32) {
            const float* p = Af + (size_t)(n0 + srow) * KDIM + k0 + scol;
            float4 a0 = *(const float4*)(p);
            float4 a1 = *(const float4*)(p + 4);
            float4 a2 = *(const float4*)(p + 8);
            float4 a3 = *(const float4*)(p + 12);
            rA0.x = (uint32_t)f2bf(a0.x) | ((uint32_t)f2bf(a0.y) << 16);
            rA0.y = (uint32_t)f2bf(a0.z) | ((uint32_t)f2bf(a0.w) << 16);
            rA0.z = (uint32_t)f2bf(a1.x) | ((uint32_t)f2bf(a1.y) << 16);
            rA0.w = (uint32_t)f2bf(a1.z) | ((uint32_t)f2bf(a1.w) << 16);
            rA1.x = (uint32_t)f2bf(a2.x) | ((uint32_t)f2bf(a2.y) << 16);
            rA1.y = (uint32_t)f2bf(a2.z) | ((uint32_t)f2bf(a2.w) << 16);
            rA1.z = (uint32_t)f2bf(a3.x) | ((uint32_t)f2bf(a3.y) << 16);
            rA1.w = (uint32_t)f2bf(a3.z) | ((uint32_t)f2bf(a3.w) << 16);
        } else {
            const uint16_t* p = Ab + (size_t)(n0 + srow) * KDIM + k0 + scol;
            rA0 = *(const uint4*)p;
            rA1 = *(const uint4*)(p + 8);
        }
    };
    auto loadB = [&](int k0) {
        const uint16_t* p = Bw + (size_t)(m0 + srow) * KDIM + k0 + scol;
        rB0 = *(const uint4*)p;
        rB1 = *(const uint4*)(p + 8);
    };
    auto dsWrite = [&](int buf) {
        *(uint4*)&smA[buf][swzg(srow, scol)]     = rA0;
        *(uint4*)&smA[buf][swzg(srow, scol + 8)] = rA1;
        *(uint4*)&smB[buf][swzg(srow, scol)]     = rB0;
        *(uint4*)&smB[buf][swzg(srow, scol + 8)] = rB1;
    };

    loadA(0); loadB(0);
    dsWrite(0);

    for (int kt = 0; kt < NK; ++kt) {
        __syncthreads();
        const int buf = kt & 1;
        const bool more = (kt + 1) < NK;
        if (more) { loadA(32 * (kt + 1)); loadB(32 * (kt + 1)); }

        bf16x8 af[4], bfg[4];
#pragma unroll
        for (int i = 0; i < 4; ++i)
            af[i] = *(const bf16x8*)&smA[buf][swzg(64 * wr + 16 * i + fr, fk8)];
#pragma unroll
        for (int j = 0; j < 4; ++j)
            bfg[j] = *(const bf16x8*)&smB[buf][swzg(64 * wc + 16 * j + fr, fk8)];
#pragma unroll
        for (int i = 0; i < 4; ++i)
#pragma unroll
            for (int j = 0; j < 4; ++j)
                acc[i][j] = __builtin_amdgcn_mfma_f32_16x16x32_bf16(af[i], bfg[j], acc[i][j], 0, 0, 0);

        if (more) dsWrite(buf ^ 1);
    }

    float biasj[4];
#pragma unroll
    for (int j = 0; j < 4; ++j) biasj[j] = bias[m0 + 64 * wc + 16 * j + fr];

#pragma unroll
    for (int i = 0; i < 4; ++i) {
#pragma unroll
        for (int r = 0; r < 4; ++r) {
            const int n = n0 + 64 * wr + 16 * i + (lane >> 4) * 4 + r;
#pragma unroll
            for (int j = 0; j < 4; ++j) {
                const int m = m0 + 64 * wc + 16 * j + fr;
                const float v = acc[i][j][r] + biasj[j];
                if constexpr (OUT_BF16)
                    ((uint16_t*)Cout)[(size_t)n * Mtot + m] = f2bf(v);
                else
                    ((float*)Cout)[(size_t)n * Mtot + m] = v;
            }
        }
    }
}

// ---------------------------------------------------------------------------
// K2 (MFMA): 96 blocks = 24 chains x 4 batch-tiles of 16. 256 thr = 4 waves.
// R6: double-buffered Act (ONE barrier/step), rcp-based gates, direct y store
// from registers, stride-incremented x/y pointers. Step critical path was
// 2453 cyc (R5, IEEE-div gate math = ~180 VALU instrs/step); now ~600-900.
// ---------------------------------------------------------------------------
__global__ __launch_bounds__(256) __attribute__((amdgpu_waves_per_eu(1)))
void lstm_rec_mfma(const uint16_t* __restrict__ xp,     // [NT][768] bf16
                   const float* __restrict__ Wih_f, const float* __restrict__ Whh_f,
                   const float* __restrict__ bih_f, const float* __restrict__ bhh_f,
                   const float* __restrict__ Wih_r, const float* __restrict__ Whh_r,
                   const float* __restrict__ bih_r, const float* __restrict__ bhh_r,
                   uint16_t* __restrict__ y)            // [NT][1536] bf16
{
    const int blk   = blockIdx.x;        // 0..95
    const int b0    = (blk & 3) * 16;
    const int chain = blk >> 2;          // 0..23
    const int head  = chain % H_;
    const int dir   = chain / H_;
    const int tid   = threadIdx.x;       // 0..255
    const int lane  = tid & 63;
    const int q     = tid >> 6;          // wave = hid group 0..3

    const float* WihP = (dir ? Wih_r : Wih_f) + (size_t)head * 256 * 64;
    const float* WhhP = (dir ? Whh_r : Whh_f) + (size_t)head * 256 * 64;
    const float* bihP = (dir ? bih_r : bih_f) + head * 256;
    const float* bhhP = (dir ? bhh_r : bhh_f) + head * 256;

    __shared__ uint16_t Act[2][16 * 128];   // double-buffered, swizzled

    const int fr = lane & 15;
    const int fk = (lane >> 4) << 3;     // 0,8,16,24

    // ---- preload W fragments: wfrag[gi][kk] (64 VGPRs, pinned) ----
    bf16x8 wfrag[4][4];
#pragma unroll
    for (int gi = 0; gi < 4; ++gi) {
        const int row = 16 * q + 64 * gi + fr;
#pragma unroll
        for (int kk = 0; kk < 4; ++kk) {
            const int k0 = 32 * kk + fk;
            const float* src = (k0 < 64) ? (WihP + row * 64 + k0)
                                         : (WhhP + row * 64 + (k0 - 64));
            float4 aa = *(const float4*)(src);
            float4 bb = *(const float4*)(src + 4);
            bf16x8 w;
            w[0] = f2bfv(aa.x); w[1] = f2bfv(aa.y); w[2] = f2bfv(aa.z); w[3] = f2bfv(aa.w);
            w[4] = f2bfv(bb.x); w[5] = f2bfv(bb.y); w[6] = f2bfv(bb.z); w[7] = f2bfv(bb.w);
            wfrag[gi][kk] = w;
        }
    }
#pragma unroll
    for (int gi = 0; gi < 4; ++gi)
#pragma unroll
        for (int kk = 0; kk < 4; ++kk)
            asm volatile("" : "+v"(wfrag[gi][kk]));

    f32x4 binit[4];
#pragma unroll
    for (int gi = 0; gi < 4; ++gi) {
#pragma unroll
        for (int r = 0; r < 4; ++r) {
            const int row = 16 * q + 64 * gi + (lane >> 4) * 4 + r;
            binit[gi][r] = bihP[row] + bhhP[row];
        }
    }

    const int tstep = dir ? -1 : 1;
    const int t0    = dir ? (T_ - 1) : 0;

    // ---- init Act[0]: h = 0, x = x(t0). thread t: batch=t>>4, d0=(t&15)*4
    const int batch = tid >> 4;
    const int d0    = (tid & 15) * 4;
    {
        uint2 z; z.x = 0; z.y = 0;
        *(uint2*)&Act[0][swzA(batch, 64 + d0)] = z;
        uint2 xv = *(const uint2*)(xp + ((size_t)(b0 + batch) * T_ + t0) * D_ + head * 64 + d0);
        *(uint2*)&Act[0][swzA(batch, d0)] = xv;
    }
    __syncthreads();

    // stride-incremented pointers
    const uint16_t* xptr = xp + ((size_t)(b0 + batch) * T_ + t0) * D_ + head * 64 + d0;
    uint16_t* yptr = y + ((size_t)(b0 + fr) * T_ + t0) * 1536 + dir * 768 + head * 64
                       + 16 * q + ((lane >> 4) << 2);
    const ptrdiff_t xstride = (ptrdiff_t)tstep * D_;
    const ptrdiff_t ystride = (ptrdiff_t)tstep * 1536;

    float cst[4] = {0.f, 0.f, 0.f, 0.f};

    for (int s = 0; s < T_; ++s) {
        // (a) prefetch next x into regs (hides under MFMA+gates)
        uint2 xstage; xstage.x = 0; xstage.y = 0;
        if (s + 1 < T_) { xptr += xstride; xstage = *(const uint2*)xptr; }

        const uint16_t* A0 = Act[s & 1];
        uint16_t*       A1 = Act[(s + 1) & 1];

        // (b) MFMA over K=128
        f32x4 acc[4];
#pragma unroll
        for (int gi = 0; gi < 4; ++gi) acc[gi] = binit[gi];
#pragma unroll
        for (int kk = 0; kk < 4; ++kk) {
            bf16x8 afr = *(const bf16x8*)&A0[swzA(fr, 32 * kk + fk)];
#pragma unroll
            for (int gi = 0; gi < 4; ++gi)
                acc[gi] = __builtin_amdgcn_mfma_f32_16x16x32_bf16(wfrag[gi][kk], afr, acc[gi], 0, 0, 0);
        }

        // (c) gates + cell update, in-register (rcp-based)
        ushort4 hpack;
#pragma unroll
        for (int r = 0; r < 4; ++r) {
            const float i_ = sigm(acc[0][r]);
            const float f_ = sigm(acc[1][r]);
            const float g_ = tanh_f(acc[2][r]);
            const float o_ = sigm(acc[3][r]);
            const float c  = f_ * cst[r] + i_ * g_;
            cst[r] = c;
            const float h = o_ * tanh_f(c);
            ((unsigned short*)&hpack)[r] = f2bf(h);
        }

        // (d) write h(t) and x(t+1) into the OTHER buffer (no barrier needed
        //     before: readers only touch A0)
        *(ushort4*)&A1[swzA(fr, 64 + 16 * q + ((lane >> 4) << 2))] = hpack;
        if (s + 1 < T_) *(uint2*)&A1[swzA(batch, d0)] = xstage;

        // (e) y store directly from registers (L2 write-combines)
        *(ushort4*)yptr = hpack;
        yptr += ystride;

        __syncthreads();   // A1 complete -> next step may read it
    }
}

// ---------------------------------------------------------------------------
extern "C" void kernel_launch(void* const* d_in, const int* in_sizes, int n_in,
                              void* d_out, int out_size, void* d_ws, size_t ws_size,
                              hipStream_t stream) {
    const float* x      = (const float*)d_in[0];
    const float* pre_W  = (const float*)d_in[1];
    const float* pre_b  = (const float*)d_in[2];
    const float* Wih_f  = (const float*)d_in[3];
    const float* Whh_f  = (const float*)d_in[4];
    const float* bih_f  = (const float*)d_in[5];
    const float* bhh_f  = (const float*)d_in[6];
    const float* Wih_r  = (const float*)d_in[7];
    const float* Whh_r  = (const float*)d_in[8];
    const float* bih_r  = (const float*)d_in[9];
    const float* bhh_r  = (const float*)d_in[10];
    const float* proj_W = (const float*)d_in[11];
    const float* proj_b = (const float*)d_in[12];
    float* out = (float*)d_out;

    uint16_t* xp      = (uint16_t*)d_ws;                  // [NT][768]  19.3 MB
    uint16_t* y       = xp + (size_t)NT_ * D_;            // [NT][1536] 38.5 MB
    uint16_t* preWbf  = y + (size_t)NT_ * 1536;           // 768*768    1.2 MB
    uint16_t* projWbf = preWbf + (size_t)D_ * D_;         // 768*1536   2.4 MB

    f32_to_bf16_k<<<256, 256, 0, stream>>>(pre_W, preWbf, D_ * D_ / 4);
    f32_to_bf16_k<<<256, 256, 0, stream>>>(proj_W, projWbf, D_ * 1536 / 4);

    dim3 g1(NT_ / 128, D_ / 128);   // (98, 6)
    gemm_nt_mfma<768, true, true><<<g1, 256, 0, stream>>>(x, preWbf, pre_b, xp, D_);

    lstm_rec_mfma<<<96, 256, 0, stream>>>(xp, Wih_f, Whh_f, bih_f, bhh_f,
                                          Wih_r, Whh_r, bih_r, bhh_r, y);

    dim3 g3(NT_ / 128, D_ / 128);   // (98, 6)
    gemm_nt_mfma<1536, false, false><<<g3, 256, 0, stream>>>(y, projWbf, proj_b, out, D_);
}

// Round 7
// 312.862 us; speedup vs baseline: 8.4158x; 1.0526x over previous
//
#include <hip/hip_runtime.h>
#include <hip/hip_bf16.h>
#include <cstdint>
#include <cstddef>

#define B_   64
#define T_   196
#define D_   768
#define H_   12
#define HID_ 64
#define NT_  (B_ * T_)   // 12544

typedef __attribute__((ext_vector_type(8))) __bf16 bf16x8;
typedef __attribute__((ext_vector_type(4))) float  f32x4;

typedef __attribute__((address_space(1))) const void* gas_t;
typedef __attribute__((address_space(3))) void*       las_t;

__device__ __forceinline__ float bf2f(uint16_t u) {
    uint32_t x = ((uint32_t)u) << 16;
    return __builtin_bit_cast(float, x);
}
__device__ __forceinline__ uint16_t f2bf(float f) {
    uint32_t x = __builtin_bit_cast(uint32_t, f);
    uint32_t r = (x + 0x7fffu + ((x >> 16) & 1u)) >> 16;
    return (uint16_t)r;
}
__device__ __forceinline__ __bf16 f2bfv(float f) {
    return __builtin_bit_cast(__bf16, f2bf(f));
}

// fast gate math: v_rcp_f32 (~1 ulp) instead of IEEE div expansion
__device__ __forceinline__ float sigm(float x) {
    return __builtin_amdgcn_rcpf(1.f + __expf(-x));
}
__device__ __forceinline__ float tanh_f(float x) {
    return 1.f - 2.f * __builtin_amdgcn_rcpf(1.f + __expf(2.f * x));
}

// XOR swizzle for [row][128] bf16 Act tiles (row stride 256B).
__device__ __forceinline__ int swzA(int row, int col) {
    int b = (row << 8) + (col << 1);
    b ^= (row & 7) << 4;
    return b >> 1;
}

// ---------------------------------------------------------------------------
// f32 -> bf16 bulk convert, float4 vectorized, grid-stride.
// ---------------------------------------------------------------------------
__global__ __launch_bounds__(256)
void f32_to_bf16_k(const float* __restrict__ in, uint16_t* __restrict__ out, int n4)
{
    int i = blockIdx.x * 256 + threadIdx.x;
    const int stride = gridDim.x * 256;
    for (; i < n4; i += stride) {
        float4 v = ((const float4*)in)[i];
        ushort4 o;
        o.x = f2bf(v.x); o.y = f2bf(v.y); o.z = f2bf(v.z); o.w = f2bf(v.w);
        ((ushort4*)out)[i] = o;
    }
}

// ---------------------------------------------------------------------------
// m97-structure MFMA NT-GEMM: C[n][m] = sum_k A[n,k]*B[m,k] + bias[m]
// A,B bf16 [.][KDIM]; 128x128 tile, 256 thr = 4 waves, 4x4 16x16x32 frags.
// Staging via global_load_lds width=16 into LINEAR [128][32] bf16 LDS,
// double-buffered, ONE barrier per K-step (barrier vmcnt-drain = known stall).
// ---------------------------------------------------------------------------
template<int KDIM, bool OUT_BF16>
__global__ __launch_bounds__(256)
void gemm_nt_gl(const uint16_t* __restrict__ A, const uint16_t* __restrict__ Bw,
                const float* __restrict__ bias, void* __restrict__ Cout, int Mtot)
{
    constexpr int NK = KDIM / 32;
    __shared__ uint16_t smA[2][128 * 32];   // 8 KB each buf
    __shared__ uint16_t smB[2][128 * 32];

    const int tid = threadIdx.x, lane = tid & 63, wv = tid >> 6;
    const int n0 = blockIdx.x * 128, m0 = blockIdx.y * 128;
    const int wr = wv >> 1, wc = wv & 1;
    const int fr = lane & 15;
    const int fk8 = (lane >> 4) * 8;

    // staging: lane covers row r0 + lane/4, bf16 col 8*(lane&3); LDS dest is
    // wave-uniform base + lane*16B == same (row,col) linearly.
    const int sr = lane >> 2;
    const int sc = (lane & 3) * 8;

    auto stage = [&](int buf, int k0) {
#pragma unroll
        for (int i = 0; i < 2; ++i) {
            const int r0 = 16 * wv + 64 * i;
            const uint16_t* ga = A  + (size_t)(n0 + r0 + sr) * KDIM + k0 + sc;
            const uint16_t* gb = Bw + (size_t)(m0 + r0 + sr) * KDIM + k0 + sc;
            __builtin_amdgcn_global_load_lds((gas_t)ga, (las_t)&smA[buf][r0 * 32], 16, 0, 0);
            __builtin_amdgcn_global_load_lds((gas_t)gb, (las_t)&smB[buf][r0 * 32], 16, 0, 0);
        }
    };

    f32x4 acc[4][4];
#pragma unroll
    for (int i = 0; i < 4; ++i)
#pragma unroll
        for (int j = 0; j < 4; ++j) acc[i][j] = (f32x4){0.f, 0.f, 0.f, 0.f};

    stage(0, 0);

    for (int kt = 0; kt < NK; ++kt) {
        const int buf = kt & 1;
        __syncthreads();   // drains vmcnt: stage(buf) landed; all waves done with buf^1
        if (kt + 1 < NK) stage(buf ^ 1, 32 * (kt + 1));

        bf16x8 af[4], bfg[4];
#pragma unroll
        for (int i = 0; i < 4; ++i)
            af[i] = *(const bf16x8*)&smA[buf][(64 * wr + 16 * i + fr) * 32 + fk8];
#pragma unroll
        for (int j = 0; j < 4; ++j)
            bfg[j] = *(const bf16x8*)&smB[buf][(64 * wc + 16 * j + fr) * 32 + fk8];
#pragma unroll
        for (int i = 0; i < 4; ++i)
#pragma unroll
            for (int j = 0; j < 4; ++j)
                acc[i][j] = __builtin_amdgcn_mfma_f32_16x16x32_bf16(af[i], bfg[j], acc[i][j], 0, 0, 0);
    }

    float biasj[4];
#pragma unroll
    for (int j = 0; j < 4; ++j) biasj[j] = bias[m0 + 64 * wc + 16 * j + fr];

#pragma unroll
    for (int i = 0; i < 4; ++i) {
#pragma unroll
        for (int r = 0; r < 4; ++r) {
            const int n = n0 + 64 * wr + 16 * i + (lane >> 4) * 4 + r;
#pragma unroll
            for (int j = 0; j < 4; ++j) {
                const int m = m0 + 64 * wc + 16 * j + fr;
                const float v = acc[i][j][r] + biasj[j];
                if constexpr (OUT_BF16)
                    ((uint16_t*)Cout)[(size_t)n * Mtot + m] = f2bf(v);
                else
                    ((float*)Cout)[(size_t)n * Mtot + m] = v;
            }
        }
    }
}

// ---------------------------------------------------------------------------
// K2 (MFMA): 96 blocks = 24 chains x 4 batch-tiles of 16. 256 thr = 4 waves.
// Double-buffered Act (one barrier/step), rcp gates, register-pinned W frags.
// R7: y-store of h(s-1) issued at top of step s (store-completion wait for
// the data register moves one full step off the critical path).
// ---------------------------------------------------------------------------
__global__ __launch_bounds__(256) __attribute__((amdgpu_waves_per_eu(1)))
void lstm_rec_mfma(const uint16_t* __restrict__ xp,     // [NT][768] bf16
                   const float* __restrict__ Wih_f, const float* __restrict__ Whh_f,
                   const float* __restrict__ bih_f, const float* __restrict__ bhh_f,
                   const float* __restrict__ Wih_r, const float* __restrict__ Whh_r,
                   const float* __restrict__ bih_r, const float* __restrict__ bhh_r,
                   uint16_t* __restrict__ y)            // [NT][1536] bf16
{
    const int blk   = blockIdx.x;        // 0..95
    const int b0    = (blk & 3) * 16;
    const int chain = blk >> 2;          // 0..23
    const int head  = chain % H_;
    const int dir   = chain / H_;
    const int tid   = threadIdx.x;       // 0..255
    const int lane  = tid & 63;
    const int q     = tid >> 6;          // wave = hid group 0..3

    const float* WihP = (dir ? Wih_r : Wih_f) + (size_t)head * 256 * 64;
    const float* WhhP = (dir ? Whh_r : Whh_f) + (size_t)head * 256 * 64;
    const float* bihP = (dir ? bih_r : bih_f) + head * 256;
    const float* bhhP = (dir ? bhh_r : bhh_f) + head * 256;

    __shared__ uint16_t Act[2][16 * 128];   // double-buffered, swizzled

    const int fr = lane & 15;
    const int fk = (lane >> 4) << 3;     // 0,8,16,24

    // ---- preload W fragments: wfrag[gi][kk] (64 VGPRs, pinned) ----
    bf16x8 wfrag[4][4];
#pragma unroll
    for (int gi = 0; gi < 4; ++gi) {
        const int row = 16 * q + 64 * gi + fr;
#pragma unroll
        for (int kk = 0; kk < 4; ++kk) {
            const int k0 = 32 * kk + fk;
            const float* src = (k0 < 64) ? (WihP + row * 64 + k0)
                                         : (WhhP + row * 64 + (k0 - 64));
            float4 aa = *(const float4*)(src);
            float4 bb = *(const float4*)(src + 4);
            bf16x8 w;
            w[0] = f2bfv(aa.x); w[1] = f2bfv(aa.y); w[2] = f2bfv(aa.z); w[3] = f2bfv(aa.w);
            w[4] = f2bfv(bb.x); w[5] = f2bfv(bb.y); w[6] = f2bfv(bb.z); w[7] = f2bfv(bb.w);
            wfrag[gi][kk] = w;
        }
    }
#pragma unroll
    for (int gi = 0; gi < 4; ++gi)
#pragma unroll
        for (int kk = 0; kk < 4; ++kk)
            asm volatile("" : "+v"(wfrag[gi][kk]));

    f32x4 binit[4];
#pragma unroll
    for (int gi = 0; gi < 4; ++gi) {
#pragma unroll
        for (int r = 0; r < 4; ++r) {
            const int row = 16 * q + 64 * gi + (lane >> 4) * 4 + r;
            binit[gi][r] = bihP[row] + bhhP[row];
        }
    }

    const int tstep = dir ? -1 : 1;
    const int t0    = dir ? (T_ - 1) : 0;

    // ---- init Act[0]: h = 0, x = x(t0). thread t: batch=t>>4, d0=(t&15)*4
    const int batch = tid >> 4;
    const int d0    = (tid & 15) * 4;
    {
        uint2 z; z.x = 0; z.y = 0;
        *(uint2*)&Act[0][swzA(batch, 64 + d0)] = z;
        uint2 xv = *(const uint2*)(xp + ((size_t)(b0 + batch) * T_ + t0) * D_ + head * 64 + d0);
        *(uint2*)&Act[0][swzA(batch, d0)] = xv;
    }
    __syncthreads();

    const uint16_t* xptr = xp + ((size_t)(b0 + batch) * T_ + t0) * D_ + head * 64 + d0;
    uint16_t* yptr = y + ((size_t)(b0 + fr) * T_ + t0) * 1536 + dir * 768 + head * 64
                       + 16 * q + ((lane >> 4) << 2);
    const ptrdiff_t xstride = (ptrdiff_t)tstep * D_;
    const ptrdiff_t ystride = (ptrdiff_t)tstep * 1536;

    float cst[4] = {0.f, 0.f, 0.f, 0.f};
    ushort4 hprev;
    uint16_t* yprev = nullptr;

    for (int s = 0; s < T_; ++s) {
        // (a0) store h(s-1): issue early, overlaps MFMA(s)
        if (s > 0) *(ushort4*)yprev = hprev;

        // (a) prefetch next x into regs (hides under MFMA+gates)
        uint2 xstage; xstage.x = 0; xstage.y = 0;
        if (s + 1 < T_) { xptr += xstride; xstage = *(const uint2*)xptr; }

        const uint16_t* A0 = Act[s & 1];
        uint16_t*       A1 = Act[(s + 1) & 1];

        // (b) MFMA over K=128
        f32x4 acc[4];
#pragma unroll
        for (int gi = 0; gi < 4; ++gi) acc[gi] = binit[gi];
#pragma unroll
        for (int kk = 0; kk < 4; ++kk) {
            bf16x8 afr = *(const bf16x8*)&A0[swzA(fr, 32 * kk + fk)];
#pragma unroll
            for (int gi = 0; gi < 4; ++gi)
                acc[gi] = __builtin_amdgcn_mfma_f32_16x16x32_bf16(wfrag[gi][kk], afr, acc[gi], 0, 0, 0);
        }

        // (c) gates + cell update, in-register
        ushort4 hpack;
#pragma unroll
        for (int r = 0; r < 4; ++r) {
            const float i_ = sigm(acc[0][r]);
            const float f_ = sigm(acc[1][r]);
            const float g_ = tanh_f(acc[2][r]);
            const float o_ = sigm(acc[3][r]);
            const float c  = f_ * cst[r] + i_ * g_;
            cst[r] = c;
            const float h = o_ * tanh_f(c);
            ((unsigned short*)&hpack)[r] = f2bf(h);
        }

        // (d) write h(t) and x(t+1) into the OTHER buffer
        *(ushort4*)&A1[swzA(fr, 64 + 16 * q + ((lane >> 4) << 2))] = hpack;
        if (s + 1 < T_) *(uint2*)&A1[swzA(batch, d0)] = xstage;

        hprev = hpack;
        yprev = yptr;
        yptr += ystride;

        __syncthreads();   // A1 complete -> next step may read it
    }
    *(ushort4*)yprev = hprev;   // final h store
}

// ---------------------------------------------------------------------------
extern "C" void kernel_launch(void* const* d_in, const int* in_sizes, int n_in,
                              void* d_out, int out_size, void* d_ws, size_t ws_size,
                              hipStream_t stream) {
    const float* x      = (const float*)d_in[0];
    const float* pre_W  = (const float*)d_in[1];
    const float* pre_b  = (const float*)d_in[2];
    const float* Wih_f  = (const float*)d_in[3];
    const float* Whh_f  = (const float*)d_in[4];
    const float* bih_f  = (const float*)d_in[5];
    const float* bhh_f  = (const float*)d_in[6];
    const float* Wih_r  = (const float*)d_in[7];
    const float* Whh_r  = (const float*)d_in[8];
    const float* bih_r  = (const float*)d_in[9];
    const float* bhh_r  = (const float*)d_in[10];
    const float* proj_W = (const float*)d_in[11];
    const float* proj_b = (const float*)d_in[12];
    float* out = (float*)d_out;

    uint16_t* xp      = (uint16_t*)d_ws;                  // [NT][768]  19.3 MB
    uint16_t* y       = xp + (size_t)NT_ * D_;            // [NT][1536] 38.5 MB
    uint16_t* preWbf  = y + (size_t)NT_ * 1536;           // 768*768    1.2 MB
    uint16_t* projWbf = preWbf + (size_t)D_ * D_;         // 768*1536   2.4 MB
    uint16_t* xbf     = y;   // aliased: x-bf16 lives in y region until lstm runs

    f32_to_bf16_k<<<256, 256, 0, stream>>>(pre_W, preWbf, D_ * D_ / 4);
    f32_to_bf16_k<<<256, 256, 0, stream>>>(proj_W, projWbf, D_ * 1536 / 4);
    f32_to_bf16_k<<<2048, 256, 0, stream>>>(x, xbf, NT_ * D_ / 4);

    dim3 g1(NT_ / 128, D_ / 128);   // (98, 6)
    gemm_nt_gl<768, true><<<g1, 256, 0, stream>>>(xbf, preWbf, pre_b, xp, D_);

    lstm_rec_mfma<<<96, 256, 0, stream>>>(xp, Wih_f, Whh_f, bih_f, bhh_f,
                                          Wih_r, Whh_r, bih_r, bhh_r, y);

    dim3 g3(NT_ / 128, D_ / 128);   // (98, 6)
    gemm_nt_gl<1536, false><<<g3, 256, 0, stream>>>(y, projWbf, proj_b, out, D_);
}